// Round 2
// baseline (306.909 us; speedup 1.0000x reference)
//
#include <hip/hip_runtime.h>
#include <math.h>

#define F_LEN 21
#define D_LEN 41
#define S_LEN 61          // F_LEN + D_LEN - 1
#define ROWS_PB 256       // rows per block == blockDim.x
#define CH 16             // staging chunk width (columns)
#define NCHUNK 4          // ceil(61/16)
#define PAD 17            // LDS row pitch (floats) to avoid bank conflicts

// One thread per (b,l) row.
// Key algebraic change vs R1: dist[d] = exp(sum_j log(term)) == prod_j term.
// Terms are convex combos of pf,pb in [0.1,1] -> product in [1e-21,1], no
// underflow, so the 861 v_log_f32 + 41 v_exp_f32 per thread are deleted.
// Column-streaming: for each s, term(j)=pb+lf[j]*(pf-pb) multiplies into
// dist[s-j]. Staging is software-pipelined: chunk c+1's global loads are in
// flight while chunk c is consumed from LDS.
__global__ __launch_bounds__(ROWS_PB, 2) void bp_kernel(
    const float* __restrict__ pf_g, const float* __restrict__ pb_g,
    const float* __restrict__ slop_g, const float* __restrict__ amp_g,
    float* __restrict__ out_dist, float* __restrict__ out_mean,
    float* __restrict__ out_ivar)
{
    __shared__ float lds_a[ROWS_PB * PAD];
    __shared__ float lds_b[ROWS_PB * PAD];

    const int tid  = threadIdx.x;
    const int row0 = blockIdx.x * ROWS_PB;
    const int r    = row0 + tid;

    // ---- prefetch chunk 0 into registers ---------------------------------
    float rf[2][CH], rb[2][CH];
    #pragma unroll
    for (int it = 0; it < CH; ++it) {
        int idx = it * ROWS_PB + tid;
        int lr  = idx >> 4;
        int lc  = idx & 15;
        if (lc < S_LEN) {                     // chunk 0: s = lc, always < 61
            size_t g = (size_t)(row0 + lr) * S_LEN + lc;
            rf[0][it] = pf_g[g];
            rb[0][it] = pb_g[g];
        }
    }

    // ---- per-row scalars (latency hidden under chunk-0 loads) ------------
    const float a  = amp_g[r];
    const float sl = slop_g[r];

    float lf[F_LEN];
    lf[10] = 0.5f;
    {
        const float E = __expf(1.0f / sl);    // e^{1/slop}; slop>=0.5 finite
        float Ek = 1.0f;
        #pragma unroll
        for (int k = 1; k <= 10; ++k) {
            Ek *= E;
            float t = (Ek - 1.0f) / (Ek + 1.0f);  // tanh(k/(2*slop))
            float d = a * t;
            lf[10 + k] = 0.5f - d;
            lf[10 - k] = 0.5f + d;
        }
    }

    float dist[D_LEN];
    #pragma unroll
    for (int d = 0; d < D_LEN; ++d) dist[d] = 1.0f;

    // ---- pipelined chunk loop --------------------------------------------
    #pragma unroll
    for (int c = 0; c < NCHUNK; ++c) {
        const int cur = c & 1;
        const int nxt = cur ^ 1;

        __syncthreads();                      // LDS free from prev consume
        #pragma unroll
        for (int it = 0; it < CH; ++it) {
            int idx = it * ROWS_PB + tid;
            int lr  = idx >> 4;
            int lc  = idx & 15;
            if (c * CH + lc < S_LEN) {
                lds_a[lr * PAD + lc] = rf[cur][it];
                lds_b[lr * PAD + lc] = rb[cur][it];
            }
        }
        __syncthreads();

        // issue next chunk's global loads (in flight during consume)
        if (c + 1 < NCHUNK) {
            #pragma unroll
            for (int it = 0; it < CH; ++it) {
                int idx = it * ROWS_PB + tid;
                int lr  = idx >> 4;
                int lc  = idx & 15;
                int s   = (c + 1) * CH + lc;
                if (s < S_LEN) {
                    size_t g = (size_t)(row0 + lr) * S_LEN + s;
                    rf[nxt][it] = pf_g[g];
                    rb[nxt][it] = pb_g[g];
                }
            }
        }

        // consume chunk c from LDS: product updates (all static indices)
        #pragma unroll
        for (int k = 0; k < CH; ++k) {
            const int s = c * CH + k;
            if (s < S_LEN) {
                float pfv = lds_a[tid * PAD + k];
                float pbv = lds_b[tid * PAD + k];
                float df  = pfv - pbv;
                #pragma unroll
                for (int j = 0; j < F_LEN; ++j) {
                    if (j <= s && s - j <= D_LEN - 1) {
                        float t = fmaf(lf[j], df, pbv);
                        dist[s - j] *= t;
                    }
                }
            }
        }
    }

    // ---- moments ----------------------------------------------------------
    float sum = 0.0f, sum1 = 0.0f, sum2 = 0.0f;
    #pragma unroll
    for (int d = 0; d < D_LEN; ++d) {
        float e = dist[d];
        sum  += e;
        sum1 += (float)d * e;
        sum2 += (float)(d * d) * e;
    }

    const float inv      = 1.0f / fmaxf(sum, 1e-12f);
    const float mean_tmp = sum1 * inv;
    const float m2       = sum2 * inv;
    const float var_tmp  = fmaf(-mean_tmp, mean_tmp, m2);

    const float two_a = 2.0f * a;
    const float at    = 0.5f * logf((1.0f + two_a) / (1.0f - two_a));
    const float min_v = fmaxf(0.5f / (at * at), sl);
    const float var   = fmaxf(var_tmp, min_v);

    out_mean[r] = mean_tmp - (float)((D_LEN - 1) / 2);
    out_ivar[r] = 1.0f / var;

    // ---- staged, coalesced store of normalized dist ----------------------
    #pragma unroll
    for (int c = 0; c < 3; ++c) {
        __syncthreads();                      // LDS free from prev phase
        #pragma unroll
        for (int k = 0; k < CH; ++k) {
            int d = c * CH + k;
            if (d < D_LEN) lds_a[tid * PAD + k] = dist[d] * inv;
        }
        __syncthreads();
        #pragma unroll
        for (int it = 0; it < CH; ++it) {
            int idx = it * ROWS_PB + tid;
            int lr  = idx >> 4;
            int lc  = idx & 15;
            int d   = c * CH + lc;
            if (d < D_LEN) {
                out_dist[(size_t)(row0 + lr) * D_LEN + d] = lds_a[lr * PAD + lc];
            }
        }
    }
}

extern "C" void kernel_launch(void* const* d_in, const int* in_sizes, int n_in,
                              void* d_out, int out_size, void* d_ws, size_t ws_size,
                              hipStream_t stream) {
    // inputs: [0] lines_feature (unused), [1] pf, [2] pb, [3] slop, [4] amp
    const float* pf   = (const float*)d_in[1];
    const float* pb   = (const float*)d_in[2];
    const float* slop = (const float*)d_in[3];
    const float* amp  = (const float*)d_in[4];

    const int rows = in_sizes[3];              // B * L = 131072

    float* out_dist = (float*)d_out;
    float* out_mean = out_dist + (size_t)rows * D_LEN;
    float* out_ivar = out_mean + rows;

    const int blocks = rows / ROWS_PB;         // 512
    bp_kernel<<<blocks, ROWS_PB, 0, stream>>>(pf, pb, slop, amp,
                                              out_dist, out_mean, out_ivar);
}

// Round 3
// 135.888 us; speedup vs baseline: 2.2585x; 2.2585x over previous
//
#include <hip/hip_runtime.h>
#include <math.h>

#define F_LEN 21
#define D_LEN 41
#define S_LEN 61          // F_LEN + D_LEN - 1
#define ROWS 128          // rows per block
#define THREADS 256       // 2 threads per row, half is wave-uniform
#define CH 16             // staging chunk width
#define PAD 17            // staging LDS pitch
#define DELEMS (ROWS * D_LEN)   // 5248

// Two threads per row (wave-uniform halves): waves 0,2 compute d=0..19 from
// s=0..39; waves 1,3 compute d=20..40 from s=20..60. dist[d] is a direct
// product (no log/exp). All register arrays statically indexed. Unnormalized
// dist goes to LDS; normalization happens in the flat coalesced copy-out.
__global__ __launch_bounds__(THREADS, 4) void bp_kernel(
    const float* __restrict__ pf_g, const float* __restrict__ pb_g,
    const float* __restrict__ slop_g, const float* __restrict__ amp_g,
    float* __restrict__ out_dist, float* __restrict__ out_mean,
    float* __restrict__ out_ivar)
{
    // [0,5248): staging (2x ROWS*PAD=4352) aliased with dist buffer
    // [5248, 5248+1280): partial sums, stride 5 to dodge bank conflicts
    // [6528, 6656): per-row inv
    __shared__ float smem[DELEMS + 2 * ROWS * 5 + ROWS];
    float* lds_a  = smem;                      // pf staging
    float* lds_b  = smem + ROWS * PAD;         // pb staging
    float* lds_d  = smem;                      // dist (after staging done)
    float* sums_l = smem + DELEMS;
    float* inv_l  = smem + DELEMS + 2 * ROWS * 5;

    const int tid  = threadIdx.x;
    const int wave = tid >> 6;
    const int lane = tid & 63;
    const int half = wave & 1;                 // wave-uniform
    const int rl   = ((wave >> 1) << 6) + lane;   // 0..127
    const int row0 = blockIdx.x * ROWS;
    const int r    = row0 + rl;

    const float a  = amp_g[r];
    const float sl = slop_g[r];

    // lf[j] = 0.5 - a*tanh((j-10)/(2*slop)) via E = e^{1/slop} powers
    float lf[F_LEN];
    lf[10] = 0.5f;
    {
        const float E = __expf(1.0f / sl);
        float Ek = 1.0f;
        #pragma unroll
        for (int k = 1; k <= 10; ++k) {
            Ek *= E;
            float t = (Ek - 1.0f) / (Ek + 1.0f);
            float dl = a * t;
            lf[10 + k] = 0.5f - dl;
            lf[10 - k] = 0.5f + dl;
        }
    }

    float pbv[41], dfv[41];                    // per-half window (local s)

    #pragma unroll
    for (int c = 0; c < 4; ++c) {
        __syncthreads();
        // cooperative coalesced stage of chunk c: 128 rows x 16 cols
        #pragma unroll
        for (int it = 0; it < 8; ++it) {
            int idx = it * THREADS + tid;      // 0..2047
            int lr  = idx >> 4;
            int lc  = idx & 15;
            int s   = c * CH + lc;
            if (s < S_LEN) {
                size_t g = (size_t)(row0 + lr) * S_LEN + s;
                lds_a[lr * PAD + lc] = pf_g[g];
                lds_b[lr * PAD + lc] = pb_g[g];
            }
        }
        __syncthreads();
        // consume into registers; all indices compile-time static
        if (half == 0) {
            if (c <= 2) {
                #pragma unroll
                for (int k = 0; k < CH; ++k) {
                    int s = c * CH + k;
                    if (s <= 39) {
                        float f = lds_a[rl * PAD + k];
                        float b = lds_b[rl * PAD + k];
                        pbv[s] = b;
                        dfv[s] = f - b;
                    }
                }
            }
        } else {
            if (c >= 1) {
                #pragma unroll
                for (int k = 0; k < CH; ++k) {
                    int s = c * CH + k;
                    if (s >= 20 && s < S_LEN) {
                        float f = lds_a[rl * PAD + k];
                        float b = lds_b[rl * PAD + k];
                        pbv[s - 20] = b;
                        dfv[s - 20] = f - b;
                    }
                }
            }
        }
    }
    __syncthreads();   // staging fully consumed before lds_d overwrites it

    float s0 = 0.0f, s1 = 0.0f, s2 = 0.0f;
    if (half == 0) {
        #pragma unroll
        for (int d = 0; d < 20; ++d) {
            float prod = fmaf(lf[0], dfv[d], pbv[d]);
            #pragma unroll
            for (int j = 1; j < F_LEN; ++j)
                prod *= fmaf(lf[j], dfv[d + j], pbv[d + j]);
            s0 += prod;
            s1 += (float)d * prod;
            s2 += (float)(d * d) * prod;
            lds_d[rl * D_LEN + d] = prod;
        }
    } else {
        #pragma unroll
        for (int dd = 0; dd < 21; ++dd) {
            const int d = dd + 20;
            float prod = fmaf(lf[0], dfv[dd], pbv[dd]);
            #pragma unroll
            for (int j = 1; j < F_LEN; ++j)
                prod *= fmaf(lf[j], dfv[dd + j], pbv[dd + j]);
            s0 += prod;
            s1 += (float)d * prod;
            s2 += (float)(d * d) * prod;
            lds_d[rl * D_LEN + d] = prod;
        }
    }
    sums_l[(half * ROWS + rl) * 5 + 0] = s0;
    sums_l[(half * ROWS + rl) * 5 + 1] = s1;
    sums_l[(half * ROWS + rl) * 5 + 2] = s2;
    __syncthreads();

    if (half == 0) {
        float t0 = s0 + sums_l[(ROWS + rl) * 5 + 0];
        float t1 = s1 + sums_l[(ROWS + rl) * 5 + 1];
        float t2 = s2 + sums_l[(ROWS + rl) * 5 + 2];
        float inv      = 1.0f / fmaxf(t0, 1e-12f);
        float mean_tmp = t1 * inv;
        float m2       = t2 * inv;
        float var_tmp  = fmaf(-mean_tmp, mean_tmp, m2);
        float two_a = 2.0f * a;
        float at    = 0.5f * logf((1.0f + two_a) / (1.0f - two_a));
        float min_v = fmaxf(0.5f / (at * at), sl);
        float var   = fmaxf(var_tmp, min_v);
        out_mean[r] = mean_tmp - (float)((D_LEN - 1) / 2);
        out_ivar[r] = 1.0f / var;
        inv_l[rl]   = inv;
    }
    __syncthreads();

    // flat coalesced copy-out with on-the-fly normalization
    #pragma unroll
    for (int it = 0; it < 21; ++it) {
        int idx = it * THREADS + tid;
        if (idx < DELEMS) {
            int lr2 = idx / D_LEN;             // magic-mul, no real div
            out_dist[(size_t)row0 * D_LEN + idx] = lds_d[idx] * inv_l[lr2];
        }
    }
}

extern "C" void kernel_launch(void* const* d_in, const int* in_sizes, int n_in,
                              void* d_out, int out_size, void* d_ws, size_t ws_size,
                              hipStream_t stream) {
    // inputs: [0] lines_feature (unused), [1] pf, [2] pb, [3] slop, [4] amp
    const float* pf   = (const float*)d_in[1];
    const float* pb   = (const float*)d_in[2];
    const float* slop = (const float*)d_in[3];
    const float* amp  = (const float*)d_in[4];

    const int rows = in_sizes[3];              // B * L = 131072

    float* out_dist = (float*)d_out;
    float* out_mean = out_dist + (size_t)rows * D_LEN;
    float* out_ivar = out_mean + rows;

    const int blocks = rows / ROWS;            // 1024
    bp_kernel<<<blocks, THREADS, 0, stream>>>(pf, pb, slop, amp,
                                              out_dist, out_mean, out_ivar);
}

// Round 4
// 28.611 us; speedup vs baseline: 10.7269x; 4.7495x over previous
//
#include <hip/hip_runtime.h>
#include <math.h>

#define F_LEN 21
#define D_LEN 41
#define S_LEN 61          // F_LEN + D_LEN - 1
#define ROWS 32           // rows per block
#define TPR 8             // threads per row
#define THREADS 256
#define PITCH 63          // LDS row pitch in floats (odd -> bank spread)
#define NELEM (ROWS * S_LEN)   // 1952

// 8 threads per row; thread q owns d = q*5 .. q*5+4 (q==7 also owns d=40).
// pf/pb stay in LDS for the whole kernel; per-thread state is only lf[21] +
// prod[6] + scalars, all statically indexed -> no spills. Column-streaming:
// for each s in the thread's window, one LDS read pair updates all its
// products. Moments combined across the 8 lanes via shfl_xor butterfly.
__global__ __launch_bounds__(THREADS, 4) void bp_kernel(
    const float* __restrict__ pf_g, const float* __restrict__ pb_g,
    const float* __restrict__ slop_g, const float* __restrict__ amp_g,
    float* __restrict__ out_dist, float* __restrict__ out_mean,
    float* __restrict__ out_ivar)
{
    __shared__ float lds_f[ROWS * PITCH];
    __shared__ float lds_b[ROWS * PITCH];

    const int tid  = threadIdx.x;
    const int rl   = tid >> 3;            // local row 0..31
    const int q    = tid & 7;             // octant within row
    const int row0 = blockIdx.x * ROWS;
    const int r    = row0 + rl;

    // ---- coalesced staging: pf/pb rows -> LDS (no register arrays) -------
    #pragma unroll
    for (int it = 0; it < 8; ++it) {
        int idx = it * THREADS + tid;     // 0 .. 2047
        if (idx < NELEM) {
            int lr = idx / S_LEN;         // magic-mul division
            int s  = idx - lr * S_LEN;
            size_t g = (size_t)row0 * S_LEN + idx;   // == (row0+lr)*61 + s
            lds_f[lr * PITCH + s] = pf_g[g];
            lds_b[lr * PITCH + s] = pb_g[g];
        }
    }

    // ---- per-row scalars (overlap staging latency) -----------------------
    const float a  = amp_g[r];
    const float sl = slop_g[r];

    float lf[F_LEN];
    lf[10] = 0.5f;
    {
        const float E = __expf(1.0f / sl);        // e^{1/slop}, slop>=0.5
        float Ek = 1.0f;
        #pragma unroll
        for (int k = 1; k <= 10; ++k) {
            Ek *= E;
            float t = __fdividef(Ek - 1.0f, Ek + 1.0f);  // tanh(k/(2*slop))
            float dl = a * t;
            lf[10 + k] = 0.5f - dl;
            lf[10 - k] = 0.5f + dl;
        }
    }

    __syncthreads();

    // ---- column-streaming product over this thread's window --------------
    const int  d0    = q * 5;
    const bool has6  = (q == 7);
    const int  base  = rl * PITCH + d0;

    float prod[6] = {1.0f, 1.0f, 1.0f, 1.0f, 1.0f, 1.0f};
    #pragma unroll
    for (int i = 0; i < 26; ++i) {        // s = d0 + i
        float f  = lds_f[base + i];
        float b  = lds_b[base + i];
        float df = f - b;
        #pragma unroll
        for (int dp = 0; dp < 6; ++dp) {
            const int j = i - dp;         // compile-time constant
            if (j >= 0 && j < F_LEN) {
                float t = fmaf(lf[j], df, b);
                if (dp == 5) t = has6 ? t : 1.0f;   // mask 6th for q<7
                prod[dp] *= t;
            }
        }
    }

    // ---- partial moments + 8-lane butterfly ------------------------------
    const float df0 = (float)d0;
    float s0 = 0.0f, s1 = 0.0f, s2 = 0.0f;
    #pragma unroll
    for (int dp = 0; dp < 6; ++dp) {
        float p = prod[dp];
        if (dp == 5) p = has6 ? p : 0.0f;
        float dv = df0 + (float)dp;
        s0 += p;
        s1 += dv * p;
        s2 += dv * dv * p;
    }
    #pragma unroll
    for (int w = 1; w < 8; w <<= 1) {
        s0 += __shfl_xor(s0, w, 64);
        s1 += __shfl_xor(s1, w, 64);
        s2 += __shfl_xor(s2, w, 64);
    }

    const float inv      = 1.0f / fmaxf(s0, 1e-12f);
    const float mean_tmp = s1 * inv;
    const float m2       = s2 * inv;
    const float var_tmp  = fmaf(-mean_tmp, mean_tmp, m2);

    const float two_a = 2.0f * a;
    const float at    = 0.5f * logf((1.0f + two_a) / (1.0f - two_a));
    const float min_v = fmaxf(0.5f / (at * at), sl);
    const float var   = fmaxf(var_tmp, min_v);

    if (q == 0) {
        out_mean[r] = mean_tmp - (float)((D_LEN - 1) / 2);
        out_ivar[r] = 1.0f / var;
    }

    // ---- normalized dist store (5 or 6 contiguous floats per thread) -----
    const size_t ob = (size_t)r * D_LEN + d0;
    #pragma unroll
    for (int dp = 0; dp < 5; ++dp)
        out_dist[ob + dp] = prod[dp] * inv;
    if (has6)
        out_dist[ob + 5] = prod[5] * inv;
}

extern "C" void kernel_launch(void* const* d_in, const int* in_sizes, int n_in,
                              void* d_out, int out_size, void* d_ws, size_t ws_size,
                              hipStream_t stream) {
    // inputs: [0] lines_feature (unused), [1] pf, [2] pb, [3] slop, [4] amp
    const float* pf   = (const float*)d_in[1];
    const float* pb   = (const float*)d_in[2];
    const float* slop = (const float*)d_in[3];
    const float* amp  = (const float*)d_in[4];

    const int rows = in_sizes[3];              // B * L = 131072

    float* out_dist = (float*)d_out;
    float* out_mean = out_dist + (size_t)rows * D_LEN;
    float* out_ivar = out_mean + rows;

    const int blocks = rows / ROWS;            // 4096
    bp_kernel<<<blocks, THREADS, 0, stream>>>(pf, pb, slop, amp,
                                              out_dist, out_mean, out_ivar);
}

// Round 5
// 26.991 us; speedup vs baseline: 11.3710x; 1.0600x over previous
//
#include <hip/hip_runtime.h>
#include <math.h>

#define F_LEN 21
#define D_LEN 41
#define S_LEN 61                 // F_LEN + D_LEN - 1
#define ROWS 32                  // rows per block
#define THREADS 256              // 8 threads per row
#define NELEM (ROWS * S_LEN)     // 1952 floats per input array per block
#define NV4   (NELEM / 4)        // 488 float4 per array
#define DOUT  (ROWS * D_LEN)     // 1312 dist floats per block
#define DV4   (DOUT / 4)         // 328 float4

// 8 threads per row; thread q owns d = q*5..q*5+4 (q==7 also d=40).
// All three memory legs vectorized:
//   global->LDS: float4 loads, interleaved (pf,pb) float2 -> ds_write_b64
//   LDS->reg:    one aligned ds_read_b64 per column (f and b together)
//   dist out:    staged in LDS (aliasing input buffer), float4 copy-out
__global__ __launch_bounds__(THREADS, 4) void bp_kernel(
    const float* __restrict__ pf_g, const float* __restrict__ pb_g,
    const float* __restrict__ slop_g, const float* __restrict__ amp_g,
    float* __restrict__ out_dist, float* __restrict__ out_mean,
    float* __restrict__ out_ivar)
{
    __shared__ float2 lds_fb[NELEM];         // 15616 B; reused for dist stage

    const int tid  = threadIdx.x;
    const int rl   = tid >> 3;               // local row 0..31
    const int q    = tid & 7;                // octant within row
    const int row0 = blockIdx.x * ROWS;
    const int r    = row0 + rl;

    // ---- staging: float4 global loads -> interleaved float2 LDS ----------
    const float4* pf4 = (const float4*)(pf_g + (size_t)row0 * S_LEN);
    const float4* pb4 = (const float4*)(pb_g + (size_t)row0 * S_LEN);
    #pragma unroll
    for (int it = 0; it < 2; ++it) {
        int idx4 = it * THREADS + tid;       // 0..487
        if (idx4 < NV4) {
            float4 f = pf4[idx4];
            float4 b = pb4[idx4];
            lds_fb[idx4 * 4 + 0] = make_float2(f.x, b.x);
            lds_fb[idx4 * 4 + 1] = make_float2(f.y, b.y);
            lds_fb[idx4 * 4 + 2] = make_float2(f.z, b.z);
            lds_fb[idx4 * 4 + 3] = make_float2(f.w, b.w);
        }
    }

    // ---- per-row scalars (overlap staging latency) -----------------------
    const float a  = amp_g[r];
    const float sl = slop_g[r];

    float lf[F_LEN];
    lf[10] = 0.5f;
    {
        const float E = __expf(1.0f / sl);          // e^{1/slop}, slop>=0.5
        float Ek = 1.0f;
        #pragma unroll
        for (int k = 1; k <= 10; ++k) {
            Ek *= E;
            float t = __fdividef(Ek - 1.0f, Ek + 1.0f);  // tanh(k/(2*slop))
            float dl = a * t;
            lf[10 + k] = 0.5f - dl;
            lf[10 - k] = 0.5f + dl;
        }
    }

    __syncthreads();

    // ---- column-streaming product over this thread's window --------------
    const int  d0   = q * 5;
    const bool has6 = (q == 7);
    const int  base = rl * S_LEN + d0;

    float prod[6] = {1.0f, 1.0f, 1.0f, 1.0f, 1.0f, 1.0f};
    #pragma unroll
    for (int i = 0; i < 26; ++i) {           // column s = d0 + i
        float2 fb = lds_fb[base + i];        // one ds_read_b64
        float  df = fb.x - fb.y;
        #pragma unroll
        for (int dp = 0; dp < 6; ++dp) {
            const int j = i - dp;            // compile-time constant
            if (j >= 0 && j < F_LEN) {
                float t = fmaf(lf[j], df, fb.y);
                if (dp == 5) t = has6 ? t : 1.0f;
                prod[dp] *= t;
            }
        }
    }

    // ---- partial moments + 8-lane butterfly ------------------------------
    const float df0 = (float)d0;
    float s0 = 0.0f, s1 = 0.0f, s2 = 0.0f;
    #pragma unroll
    for (int dp = 0; dp < 6; ++dp) {
        float p = prod[dp];
        if (dp == 5) p = has6 ? p : 0.0f;
        float dv = df0 + (float)dp;
        s0 += p;
        s1 += dv * p;
        s2 += dv * dv * p;
    }
    #pragma unroll
    for (int w = 1; w < 8; w <<= 1) {
        s0 += __shfl_xor(s0, w, 64);
        s1 += __shfl_xor(s1, w, 64);
        s2 += __shfl_xor(s2, w, 64);
    }

    const float inv      = 1.0f / fmaxf(s0, 1e-12f);
    const float mean_tmp = s1 * inv;
    const float m2       = s2 * inv;
    const float var_tmp  = fmaf(-mean_tmp, mean_tmp, m2);

    const float two_a = 2.0f * a;
    const float at    = 0.5f * logf((1.0f + two_a) / (1.0f - two_a));
    const float min_v = fmaxf(0.5f / (at * at), sl);
    const float var   = fmaxf(var_tmp, min_v);

    if (q == 0) {
        out_mean[r] = mean_tmp - (float)((D_LEN - 1) / 2);
        out_ivar[r] = 1.0f / var;
    }

    // ---- dist: stage normalized values in LDS, then float4 copy-out ------
    __syncthreads();                          // all reads of lds_fb done
    float* ldsd = (float*)lds_fb;             // alias: 1312 floats needed
    #pragma unroll
    for (int dp = 0; dp < 5; ++dp)
        ldsd[rl * D_LEN + d0 + dp] = prod[dp] * inv;
    if (has6)
        ldsd[rl * D_LEN + 40] = prod[5] * inv;
    __syncthreads();

    const float4* ld4 = (const float4*)ldsd;
    float4* o4 = (float4*)(out_dist + (size_t)row0 * D_LEN);  // 16B aligned
    #pragma unroll
    for (int it = 0; it < 2; ++it) {
        int idx4 = it * THREADS + tid;        // 0..327
        if (idx4 < DV4) o4[idx4] = ld4[idx4];
    }
}

extern "C" void kernel_launch(void* const* d_in, const int* in_sizes, int n_in,
                              void* d_out, int out_size, void* d_ws, size_t ws_size,
                              hipStream_t stream) {
    // inputs: [0] lines_feature (unused), [1] pf, [2] pb, [3] slop, [4] amp
    const float* pf   = (const float*)d_in[1];
    const float* pb   = (const float*)d_in[2];
    const float* slop = (const float*)d_in[3];
    const float* amp  = (const float*)d_in[4];

    const int rows = in_sizes[3];              // B * L = 131072

    float* out_dist = (float*)d_out;
    float* out_mean = out_dist + (size_t)rows * D_LEN;
    float* out_ivar = out_mean + rows;

    const int blocks = rows / ROWS;            // 4096
    bp_kernel<<<blocks, THREADS, 0, stream>>>(pf, pb, slop, amp,
                                              out_dist, out_mean, out_ivar);
}